// Round 1
// baseline (272.543 us; speedup 1.0000x reference)
//
#include <hip/hip_runtime.h>
#include <math.h>

#define K_KP 17
#define HM 56
#define HW (HM * HM)          // 3136
#define N_ROWS 1024
#define NK_ROWS (N_ROWS * K_KP)   // 17408
#define KP_BLOCKS ((NK_ROWS + 3) / 4)  // 4352, 4 waves/block, 1 wave/row
#define C_CLS 8
#define IGNORE_LABEL 7
#define BETA_C (1.0f / 9.0f)

// ws layout (floats):
//   [0..255]    kp nll sum slots
//   [256..511]  kp valid-count slots
//   [512]       cls nll sum
//   [513]       cls keep count
//   [514]       box smooth-l1 sum
#define WS_FLOATS 515

__global__ __launch_bounds__(256) void roiheads_fused(
    const float* __restrict__ class_logits,      // (1024, 8)
    const float* __restrict__ box_regression,    // (1024, 32)
    const float* __restrict__ regression_targets,// (1024, 4)
    const float* __restrict__ proposals,         // (1024, 4)
    const float* __restrict__ gt_keypoints,      // (256, 17, 3)
    const float* __restrict__ keypoint_logits,   // (1024, 17, 56, 56)
    const int*   __restrict__ labels,            // (1024,)
    const int*   __restrict__ kmi,               // (1024,)
    float* __restrict__ ws)
{
    const int bid = blockIdx.x;
    const int tid = threadIdx.x;

    if (bid < KP_BLOCKS) {
        // ---- keypoint CE: one wave per (n,k) row ----
        const int lane = tid & 63;
        const int wid  = tid >> 6;
        const int r = bid * 4 + wid;
        if (r >= NK_ROWS) return;

        const int n = r / K_KP;
        const int k = r - n * K_KP;

        // wave-uniform metadata (all lanes load same addrs -> broadcast)
        const int g = kmi[n];
        const float* kp = gt_keypoints + ((size_t)g * K_KP + k) * 3;
        const float kx  = kp[0];
        const float ky  = kp[1];
        const float vis = kp[2];
        const float px1 = proposals[n * 4 + 0];
        const float py1 = proposals[n * 4 + 1];
        const float px2 = proposals[n * 4 + 2];
        const float py2 = proposals[n * 4 + 3];
        const float sx = (float)HM / (px2 - px1);
        const float sy = (float)HM / (py2 - py1);
        int xi = (int)floorf((kx - px1) * sx);
        int yi = (int)floorf((ky - py1) * sy);
        if (kx == px2) xi = HM - 1;
        if (ky == py2) yi = HM - 1;
        const bool valid = (xi >= 0) & (yi >= 0) & (xi < HM) & (yi < HM) & (vis > 0.0f);
        if (!valid) return;   // wave-uniform: ~99.9% of waves exit here

        const int lin = yi * HM + xi;
        const float4* rowp = (const float4*)(keypoint_logits + (size_t)r * HW);

        // one-pass online softmax over 784 float4s (lane-strided)
        float m = -INFINITY, s = 0.0f;
        #pragma unroll
        for (int it = 0; it < 13; ++it) {
            const int idx = it * 64 + lane;
            if (idx < HW / 4) {
                const float4 v = rowp[idx];
                float vals[4] = {v.x, v.y, v.z, v.w};
                #pragma unroll
                for (int j = 0; j < 4; ++j) {
                    const float x = vals[j];
                    if (x > m) { s = s * expf(m - x) + 1.0f; m = x; }
                    else       { s += expf(x - m); }
                }
            }
        }
        // wave (m,s) reduction
        #pragma unroll
        for (int off = 32; off > 0; off >>= 1) {
            const float om = __shfl_down(m, off, 64);
            const float os = __shfl_down(s, off, 64);
            const float nm = fmaxf(m, om);
            s = s * expf(m - nm) + os * expf(om - nm);
            m = nm;
        }
        if (lane == 0) {
            const float xt = keypoint_logits[(size_t)r * HW + lin];
            const float nll = m + logf(s) - xt;   // -(xt - m - log(sumexp))
            atomicAdd(&ws[r & 255], nll);
            atomicAdd(&ws[256 + (r & 255)], 1.0f);
        }
    } else {
        // ---- classification CE + box smooth-L1: one thread per proposal ----
        const int n = (bid - KP_BLOCKS) * 256 + tid;   // [0, 1024)
        const int label = labels[n];

        const float* cl = class_logits + (size_t)n * C_CLS;
        float m = cl[0];
        #pragma unroll
        for (int j = 1; j < C_CLS; ++j) m = fmaxf(m, cl[j]);
        float s = 0.0f;
        #pragma unroll
        for (int j = 0; j < C_CLS; ++j) s += expf(cl[j] - m);
        const float nll = m + logf(s) - cl[label];
        const float keep = (label != IGNORE_LABEL) ? 1.0f : 0.0f;
        float cls_part = keep * nll;
        float keep_part = keep;

        float box_part = 0.0f;
        if (label > 0) {
            #pragma unroll
            for (int j = 0; j < 4; ++j) {
                const float d = box_regression[(size_t)n * 32 + label * 4 + j]
                              - regression_targets[(size_t)n * 4 + j];
                const float ad = fabsf(d);
                box_part += (ad < BETA_C) ? 0.5f * d * d / BETA_C : ad - 0.5f * BETA_C;
            }
        }

        #pragma unroll
        for (int off = 32; off > 0; off >>= 1) {
            cls_part  += __shfl_down(cls_part,  off, 64);
            keep_part += __shfl_down(keep_part, off, 64);
            box_part  += __shfl_down(box_part,  off, 64);
        }
        if ((tid & 63) == 0) {
            atomicAdd(&ws[512], cls_part);
            atomicAdd(&ws[513], keep_part);
            atomicAdd(&ws[514], box_part);
        }
    }
}

__global__ __launch_bounds__(256) void roiheads_finalize(
    const float* __restrict__ ws, float* __restrict__ out)
{
    __shared__ float sm_s[4];
    __shared__ float sm_c[4];
    const int tid = threadIdx.x;
    float ks = ws[tid];
    float kc = ws[256 + tid];
    #pragma unroll
    for (int off = 32; off > 0; off >>= 1) {
        ks += __shfl_down(ks, off, 64);
        kc += __shfl_down(kc, off, 64);
    }
    const int wid = tid >> 6;
    if ((tid & 63) == 0) { sm_s[wid] = ks; sm_c[wid] = kc; }
    __syncthreads();
    if (tid == 0) {
        const float S  = sm_s[0] + sm_s[1] + sm_s[2] + sm_s[3];
        const float Cn = sm_c[0] + sm_c[1] + sm_c[2] + sm_c[3];
        out[0] = ws[512] / fmaxf(ws[513], 1.0f);
        out[1] = ws[514] / (float)N_ROWS;
        out[2] = S / fmaxf(Cn, 1.0f);
    }
}

extern "C" void kernel_launch(void* const* d_in, const int* in_sizes, int n_in,
                              void* d_out, int out_size, void* d_ws, size_t ws_size,
                              hipStream_t stream) {
    const float* class_logits       = (const float*)d_in[0];
    const float* box_regression     = (const float*)d_in[1];
    const float* regression_targets = (const float*)d_in[2];
    const float* proposals          = (const float*)d_in[3];
    const float* gt_keypoints       = (const float*)d_in[4];
    const float* keypoint_logits    = (const float*)d_in[5];
    const int*   labels             = (const int*)d_in[6];
    const int*   kmi                = (const int*)d_in[7];
    float* ws  = (float*)d_ws;
    float* out = (float*)d_out;

    hipMemsetAsync(ws, 0, WS_FLOATS * sizeof(float), stream);

    const int total_blocks = KP_BLOCKS + (N_ROWS / 256);  // 4352 + 4
    roiheads_fused<<<total_blocks, 256, 0, stream>>>(
        class_logits, box_regression, regression_targets, proposals,
        gt_keypoints, keypoint_logits, labels, kmi, ws);

    roiheads_finalize<<<1, 256, 0, stream>>>(ws, out);
}